// Round 9
// baseline (188.680 us; speedup 1.0000x reference)
//
#include <hip/hip_runtime.h>
#include <stdint.h>

typedef unsigned short u16;
typedef short bf8 __attribute__((ext_vector_type(8)));    // 8 bf16 (bit pattern)
typedef float f4 __attribute__((ext_vector_type(4)));
typedef unsigned int u32x4 __attribute__((ext_vector_type(4)));
typedef short s8v __attribute__((ext_vector_type(8)));

#define TTOK 8192
#define HD   1024
#define NE   8

static __device__ __forceinline__ u16 f2bf(float f) {
  union { float f; uint32_t u; } v; v.f = f;
  return (u16)((v.u + 0x7fffu + ((v.u >> 16) & 1u)) >> 16);   // RNE
}

// scale two packed bf16 by w, RNE back to packed bf16
static __device__ __forceinline__ uint32_t scale2bf(uint32_t v, float w) {
  union { float f; uint32_t u; } lo, hi;
  lo.u = v << 16;
  hi.u = v & 0xffff0000u;
  lo.f *= w; hi.f *= w;
  const uint32_t lr = (lo.u + 0x7fffu + ((lo.u >> 16) & 1u)) >> 16;
  const uint32_t hr = (hi.u + 0x7fffu + ((hi.u >> 16) & 1u)) & 0xffff0000u;
  return lr | hr;
}

// ---------------- gating (fp32) + x -> bf16 conversion ----------------
__global__ __launch_bounds__(256) void gate_conv_kernel(
    const float* __restrict__ x, const float* __restrict__ gw,
    const float* __restrict__ gb, float* __restrict__ wout,
    u16* __restrict__ abf)
{
  const int t    = blockIdx.x * 4 + (threadIdx.x >> 6);
  const int lane = threadIdx.x & 63;
  const float* xr = x + (size_t)t * HD;
  float p[NE];
#pragma unroll
  for (int e = 0; e < NE; ++e) p[e] = 0.f;
#pragma unroll 4
  for (int h = lane; h < HD; h += 64) {
    const float xv = xr[h];
    abf[(size_t)t * HD + h] = f2bf(xv);
    const float* g = gw + (size_t)h * NE;
#pragma unroll
    for (int e = 0; e < NE; ++e) p[e] += xv * g[e];
  }
#pragma unroll
  for (int e = 0; e < NE; ++e) {
#pragma unroll
    for (int off = 32; off > 0; off >>= 1)
      p[e] += __shfl_xor(p[e], off, 64);
    p[e] += gb[e];
  }
  float m = p[0];
#pragma unroll
  for (int e = 1; e < NE; ++e) m = fmaxf(m, p[e]);
  float s = 0.f;
#pragma unroll
  for (int e = 0; e < NE; ++e) { p[e] = expf(p[e] - m); s += p[e]; }
  const float inv = 1.f / s;
  if (lane == 0) {
#pragma unroll
    for (int e = 0; e < NE; ++e) wout[t * NE + e] = p[e] * inv;
  }
}

// ------------- expert_w [E][H][H] fp32 -> Wt [E][d][h] bf16 (transposed) -------------
__global__ __launch_bounds__(256) void wconv_kernel(
    const float* __restrict__ ew, u16* __restrict__ wt)
{
  __shared__ u16 tile[64][66];
  const int e  = blockIdx.z;
  const int h0 = blockIdx.y * 64;
  const int d0 = blockIdx.x * 64;
  const int c  = threadIdx.x & 63;
  const int r0 = threadIdx.x >> 6;
  const float* src = ew + (size_t)e * HD * HD;
  u16* dst = wt + (size_t)e * HD * HD;
#pragma unroll
  for (int i = 0; i < 16; ++i) {
    const int r = i * 4 + r0;
    tile[r][c] = f2bf(src[(size_t)(h0 + r) * HD + d0 + c]);
  }
  __syncthreads();
#pragma unroll
  for (int i = 0; i < 16; ++i) {
    const int r = i * 4 + r0;
    dst[(size_t)(d0 + r) * HD + h0 + c] = tile[c][r];
  }
}

// --- fused dense-MoE GEMM — 256x256 block, 8 waves of 128x64, gate-folded-A, e-split(2) ---
// half h computes P_h[t,d] = sum_{e in half} (w[t,e]*A[t,:]) . Wt[e][d][:]
// half 0 -> out fp32 (+ full 8-expert bias);  half 1 -> p1 bf16;  combine: out += p1
#define BM 256
#define BN 256
#define BK 64

#define MM(a_, b_, c_) __builtin_amdgcn_mfma_f32_16x16x32_bf16((a_), (b_), (c_), 0, 0, 0)

// frag read: row&7 == l15&7; granule slot = (kk*4+lhi)^(l15&7)  (involution w/ staging)
#define LDFA(off_, m_, kk_) (*(const bf8*)((const char*)As + (off_) + \
    (size_t)(wrb + (m_) * 16 + l15) * 128 + ((((kk_) * 4 + lhi) ^ (l15 & 7)) << 4)))
#define LDFB(off_, n_, kk_) (*(const bf8*)((const char*)Bs + (off_) + \
    (size_t)(wcb + (n_) * 16 + l15) * 128 + ((((kk_) * 4 + lhi) ^ (l15 & 7)) << 4)))

#define GL(srcp_, dstp_) __builtin_amdgcn_global_load_lds( \
    (const __attribute__((address_space(1))) void*)(srcp_), \
    (__attribute__((address_space(3))) void*)(dstp_), 16, 0, 0)

// 16 MFMAs for m-rows M_..M_+3 x n 0..3 (M_ is a literal 0 or 4)
#define MFMA16(M_)                                        \
    acc[(M_)+0][0] = MM(a0, b0, acc[(M_)+0][0]);          \
    acc[(M_)+1][0] = MM(a1, b0, acc[(M_)+1][0]);          \
    acc[(M_)+2][0] = MM(a2, b0, acc[(M_)+2][0]);          \
    acc[(M_)+3][0] = MM(a3, b0, acc[(M_)+3][0]);          \
    acc[(M_)+0][1] = MM(a0, b1, acc[(M_)+0][1]);          \
    acc[(M_)+1][1] = MM(a1, b1, acc[(M_)+1][1]);          \
    acc[(M_)+2][1] = MM(a2, b1, acc[(M_)+2][1]);          \
    acc[(M_)+3][1] = MM(a3, b1, acc[(M_)+3][1]);          \
    acc[(M_)+0][2] = MM(a0, b2, acc[(M_)+0][2]);          \
    acc[(M_)+1][2] = MM(a1, b2, acc[(M_)+1][2]);          \
    acc[(M_)+2][2] = MM(a2, b2, acc[(M_)+2][2]);          \
    acc[(M_)+3][2] = MM(a3, b2, acc[(M_)+3][2]);          \
    acc[(M_)+0][3] = MM(a0, b3, acc[(M_)+0][3]);          \
    acc[(M_)+1][3] = MM(a1, b3, acc[(M_)+1][3]);          \
    acc[(M_)+2][3] = MM(a2, b3, acc[(M_)+2][3]);          \
    acc[(M_)+3][3] = MM(a3, b3, acc[(M_)+3][3]);

#define RD_A(m0_, kk_)                                    \
    a0 = LDFA(curO, (m0_)+0, kk_);                        \
    a1 = LDFA(curO, (m0_)+1, kk_);                        \
    a2 = LDFA(curO, (m0_)+2, kk_);                        \
    a3 = LDFA(curO, (m0_)+3, kk_);
#define RD_B(kk_)                                         \
    b0 = LDFB(curO, 0, kk_);                              \
    b1 = LDFB(curO, 1, kk_);                              \
    b2 = LDFB(curO, 2, kk_);                              \
    b3 = LDFB(curO, 3, kk_);

#define A_WRITE(aL_, wA_, off_)  {                                   \
    u32x4 t_;                                                        \
    t_[0] = scale2bf((aL_)[0], wA_);                                 \
    t_[1] = scale2bf((aL_)[1], wA_);                                 \
    t_[2] = scale2bf((aL_)[2], wA_);                                 \
    t_[3] = scale2bf((aL_)[3], wA_);                                 \
    *(u32x4*)((char*)As + stO + awoff + (off_)) = t_;                \
  }

#define BAR       __builtin_amdgcn_s_barrier();
#define LGKM0     asm volatile("s_waitcnt lgkmcnt(0)" ::: "memory");
#define VM0       asm volatile("s_waitcnt vmcnt(0)" ::: "memory");
#define VMC4      asm volatile("s_waitcnt vmcnt(4)" ::: "memory");
#define PRIO1     __builtin_amdgcn_s_setprio(1);
#define PRIO0     __builtin_amdgcn_s_setprio(0);

__global__ __launch_bounds__(512, 2) void moe_gemm_kernel(
    const u16* __restrict__ A,      // [T][H] bf16
    const u16* __restrict__ Wt,     // [E][H(d)][H(k)] bf16
    const float* __restrict__ wg,   // [T][E]
    const float* __restrict__ eb,   // [E][H]
    float* __restrict__ out,        // [T][H] fp32   (half 0)
    u16* __restrict__ p1)           // [T][H] bf16   (half 1)
{
  __shared__ u16 As[2 * BM * BK];   // 64 KB (double buffer, 32 KB each)
  __shared__ u16 Bs[2 * BN * BK];   // 64 KB
  __shared__ float wgs[BM * 9];     //  9 KB gate weights, stride-9

  const int bid  = blockIdx.x;
  const int xcd  = bid & 7;
  const int j    = bid >> 3;                 // 0..31
  const int bm   = xcd * 4 + (j & 3);        // 0..31
  const int r2   = j >> 2;                   // 0..7
  const int bn   = r2 & 3;                   // 0..3
  const int half = r2 >> 2;                  // 0..1
  const int eBase = half * 4;
  const int row0  = bm * BM;
  const int col0  = bn * BN;

  const int tid  = threadIdx.x;
  const int lane = tid & 63;
  const int wid  = tid >> 6;
  const int wr   = wid >> 2;        // 0..1
  const int wc   = wid & 3;         // 0..3
  const int l15  = lane & 15;
  const int lhi  = lane >> 4;
  const int wrb  = wr * 128;        // wave tile 128 rows
  const int wcb  = wc * 64;         // x 64 cols

  // staging: 512 thr x 16B = 8 KB/round = 64 rows; 4 rounds per tile side
  const int row_in = tid >> 3;                       // 0..63
  const int gsw    = (tid & 7) ^ (row_in & 7);
  const int awoff  = row_in * 128 + gsw * 16;        // swizzled A ds_write offset
  // A source UNswizzled (reg-stage applies swizzle at ds_write); B source pre-swizzled
  const u16* aSrc0 = A  + (size_t)(row0 + row_in) * HD + (tid & 7) * 8;
  const u16* bSrc0 = Wt + (size_t)(col0 + row_in) * HD + gsw * 8;

  // gate weights -> padded LDS table (256 rows x 8 experts, stride 9)
  {
    const f4 v = *(const f4*)(wg + (size_t)row0 * NE + tid * 4);
    const int i0 = tid * 4;
#pragma unroll
    for (int k = 0; k < 4; ++k) {
      const int idx = i0 + k;
      wgs[(idx >> 3) * 9 + (idx & 7)] = v[k];
    }
  }
  LGKM0
  BAR   // cross-thread wgs visibility

  float wA0 = wgs[(row_in +   0) * 9 + eBase];
  float wA1 = wgs[(row_in +  64) * 9 + eBase];
  float wA2 = wgs[(row_in + 128) * 9 + eBase];
  float wA3 = wgs[(row_in + 192) * 9 + eBase];
  size_t esHH = (size_t)eBase * (HD * HD);

  const f4 fz = {0.f, 0.f, 0.f, 0.f};
  f4 acc[8][4];
#pragma unroll
  for (int i = 0; i < 8; ++i)
#pragma unroll
    for (int k = 0; k < 4; ++k) acc[i][k] = fz;

  int curO = 0, stO = 32768;
  u32x4 aL0, aL1, aL2, aL3;
  bf8 a0, a1, a2, a3, b0, b1, b2, b3;

  // prologue: stage tile 0 (expert eBase, kcol 0) into buffer 0
  {
    aL0 = *(const u32x4*)(aSrc0);
    aL1 = *(const u32x4*)(aSrc0 + 65536);
    aL2 = *(const u32x4*)(aSrc0 + 131072);
    aL3 = *(const u32x4*)(aSrc0 + 196608);
    const u16* bS_ = bSrc0 + esHH;
    char* bd_ = (char*)Bs + tid * 16;
    GL(bS_, bd_); GL(bS_ + 65536, bd_ + 8192);
    GL(bS_ + 131072, bd_ + 16384); GL(bS_ + 196608, bd_ + 24576);
    VMC4   // aL landed; 4 B-gloads outstanding
    { const int svO = stO; stO = 0;
      A_WRITE(aL0, wA0, 0) A_WRITE(aL1, wA1, 8192)
      A_WRITE(aL2, wA2, 16384) A_WRITE(aL3, wA3, 24576)
      stO = svO; }
    VM0 LGKM0 BAR
  }

  for (int q = 0; q < 63; ++q) {
    const int sq    = q + 1;
    const int kcol_ = (sq & 15) << 6;
    if ((sq & 15) == 0) {
      const int es_ = eBase + (sq >> 4);
      esHH = (size_t)es_ * (HD * HD);
      wA0 = wgs[(row_in +   0) * 9 + es_];
      wA1 = wgs[(row_in +  64) * 9 + es_];
      wA2 = wgs[(row_in + 128) * 9 + es_];
      wA3 = wgs[(row_in + 192) * 9 + es_];
    }
    // ---- P0: kk0, m0-3 ; issue A-loads(q+1) ----
    RD_A(0, 0) RD_B(0)
    {
      const u16* aS_ = aSrc0 + kcol_;
      aL0 = *(const u32x4*)(aS_);
      aL1 = *(const u32x4*)(aS_ + 65536);
      aL2 = *(const u32x4*)(aS_ + 131072);
      aL3 = *(const u32x4*)(aS_ + 196608);
    }
    BAR LGKM0 PRIO1
    MFMA16(0)
    PRIO0 BAR
    // ---- P1: kk0, m4-7 ; issue B-gloads(q+1) ----
    RD_A(4, 0)
    {
      const u16* bS_ = bSrc0 + esHH + kcol_;
      char* bd_ = (char*)Bs + stO + tid * 16;
      GL(bS_, bd_); GL(bS_ + 65536, bd_ + 8192);
      GL(bS_ + 131072, bd_ + 16384); GL(bS_ + 196608, bd_ + 24576);
    }
    BAR LGKM0 PRIO1
    MFMA16(4)
    PRIO0 BAR
    // ---- P2: kk1, m0-3 ; scale+write A(q+1) ----
    RD_A(0, 1) RD_B(1)
    VMC4
    A_WRITE(aL0, wA0, 0) A_WRITE(aL1, wA1, 8192)
    A_WRITE(aL2, wA2, 16384) A_WRITE(aL3, wA3, 24576)
    BAR LGKM0 PRIO1
    MFMA16(0)
    PRIO0 BAR
    // ---- P3: kk1, m4-7 ; drain B(q+1) at tile end ----
    RD_A(4, 1)
    BAR LGKM0 PRIO1
    MFMA16(4)
    PRIO0
    VM0 BAR
    { const int t_ = curO; curO = stO; stO = t_; }
  }
  // tail tile q = 63 (no staging)
  RD_A(0, 0) RD_B(0)
  BAR LGKM0 PRIO1
  MFMA16(0)
  PRIO0 BAR
  RD_A(4, 0)
  BAR LGKM0 PRIO1
  MFMA16(4)
  PRIO0 BAR
  RD_A(0, 1) RD_B(1)
  BAR LGKM0 PRIO1
  MFMA16(0)
  PRIO0 BAR
  RD_A(4, 1)
  BAR LGKM0 PRIO1
  MFMA16(4)
  PRIO0

  // epilogue (C/D: col = lane&15, row = (lane>>4)*4 + reg)
  if (half == 0) {
    float ebv[4][8];
#pragma unroll
    for (int ni = 0; ni < 4; ++ni) {
      const int d = col0 + wcb + ni * 16 + l15;
#pragma unroll
      for (int e2 = 0; e2 < NE; ++e2) ebv[ni][e2] = eb[(size_t)e2 * HD + d];
    }
#pragma unroll
    for (int mi = 0; mi < 8; ++mi) {
      const int r_ = wrb + mi * 16 + lhi * 4;
#pragma unroll
      for (int jj = 0; jj < 4; ++jj) {
        const int t = row0 + r_ + jj;
        const float* wrow = &wgs[(r_ + jj) * 9];
#pragma unroll
        for (int ni = 0; ni < 4; ++ni) {
          const float bias =
              wrow[0] * ebv[ni][0] + wrow[1] * ebv[ni][1] +
              wrow[2] * ebv[ni][2] + wrow[3] * ebv[ni][3] +
              wrow[4] * ebv[ni][4] + wrow[5] * ebv[ni][5] +
              wrow[6] * ebv[ni][6] + wrow[7] * ebv[ni][7];
          const int d = col0 + wcb + ni * 16 + l15;
          out[(size_t)t * HD + d] = acc[mi][ni][jj] + bias;
        }
      }
    }
  } else {
#pragma unroll
    for (int mi = 0; mi < 8; ++mi) {
      const int r_ = wrb + mi * 16 + lhi * 4;
#pragma unroll
      for (int jj = 0; jj < 4; ++jj) {
        const int t = row0 + r_ + jj;
#pragma unroll
        for (int ni = 0; ni < 4; ++ni) {
          const int d = col0 + wcb + ni * 16 + l15;
          p1[(size_t)t * HD + d] = f2bf(acc[mi][ni][jj]);
        }
      }
    }
  }
}

// ---------------- combine: out += p1 (bf16) ----------------
__global__ __launch_bounds__(256) void combine_kernel(
    float* __restrict__ out, const u16* __restrict__ p1)
{
  const size_t i8 = ((size_t)blockIdx.x * 256 + threadIdx.x) * 8;
  f4 o0 = *(f4*)(out + i8);
  f4 o1 = *(f4*)(out + i8 + 4);
  const s8v pv = *(const s8v*)(p1 + i8);
#pragma unroll
  for (int k = 0; k < 4; ++k) {
    union { uint32_t u; float f; } c0, c1;
    c0.u = ((uint32_t)(u16)pv[k]) << 16;
    c1.u = ((uint32_t)(u16)pv[k + 4]) << 16;
    o0[k] += c0.f;
    o1[k] += c1.f;
  }
  *(f4*)(out + i8) = o0;
  *(f4*)(out + i8 + 4) = o1;
}

extern "C" void kernel_launch(void* const* d_in, const int* in_sizes, int n_in,
                              void* d_out, int out_size, void* d_ws, size_t ws_size,
                              hipStream_t stream) {
  const float* x  = (const float*)d_in[0];   // [4,2048,1024]
  const float* gw = (const float*)d_in[1];   // [1024,8]
  const float* gb = (const float*)d_in[2];   // [8]
  const float* ew = (const float*)d_in[3];   // [8,1024,1024]
  const float* eb = (const float*)d_in[4];   // [8,1024]
  float* out = (float*)d_out;                // [4,2048,1024] fp32

  char* ws = (char*)d_ws;
  u16*   abf   = (u16*)ws;                                // 16 MB bf16 x
  u16*   wt    = (u16*)(ws + (size_t)16 * 1024 * 1024);   // 16 MB bf16 Wt
  float* wgate = (float*)(ws + (size_t)32 * 1024 * 1024); // 256 KB gate weights
  u16*   p1    = (u16*)(ws + (size_t)34 * 1024 * 1024);   // 16.8 MB bf16 partial

  gate_conv_kernel<<<dim3(TTOK / 4), dim3(256), 0, stream>>>(x, gw, gb, wgate, abf);
  wconv_kernel<<<dim3(16, 16, 8), dim3(256), 0, stream>>>(ew, wt);
  moe_gemm_kernel<<<dim3(256), dim3(512), 0, stream>>>(abf, wt, wgate, eb, out, p1);
  combine_kernel<<<dim3(TTOK * HD / (256 * 8)), dim3(256), 0, stream>>>(out, p1);
}

// Round 10
// 154.447 us; speedup vs baseline: 1.2217x; 1.2217x over previous
//
#include <hip/hip_runtime.h>
#include <stdint.h>

typedef unsigned short u16;
typedef short bf8 __attribute__((ext_vector_type(8)));   // 8 bf16 (bit pattern)
typedef float f4 __attribute__((ext_vector_type(4)));

#define TTOK 8192
#define HD   1024
#define NE   8

static __device__ __forceinline__ u16 f2bf(float f) {
  union { float f; uint32_t u; } v; v.f = f;
  return (u16)((v.u + 0x7fffu + ((v.u >> 16) & 1u)) >> 16);   // RNE
}

// ---------------- gating (fp32) + x -> bf16 conversion ----------------
__global__ __launch_bounds__(256) void gate_conv_kernel(
    const float* __restrict__ x, const float* __restrict__ gw,
    const float* __restrict__ gb, float* __restrict__ wout,
    u16* __restrict__ abf)
{
  const int t    = blockIdx.x * 4 + (threadIdx.x >> 6);
  const int lane = threadIdx.x & 63;
  const float* xr = x + (size_t)t * HD;
  float p[NE];
#pragma unroll
  for (int e = 0; e < NE; ++e) p[e] = 0.f;
#pragma unroll 4
  for (int h = lane; h < HD; h += 64) {
    const float xv = xr[h];
    abf[(size_t)t * HD + h] = f2bf(xv);
    const float* g = gw + (size_t)h * NE;
#pragma unroll
    for (int e = 0; e < NE; ++e) p[e] += xv * g[e];
  }
#pragma unroll
  for (int e = 0; e < NE; ++e) {
#pragma unroll
    for (int off = 32; off > 0; off >>= 1)
      p[e] += __shfl_xor(p[e], off, 64);
    p[e] += gb[e];
  }
  float m = p[0];
#pragma unroll
  for (int e = 1; e < NE; ++e) m = fmaxf(m, p[e]);
  float s = 0.f;
#pragma unroll
  for (int e = 0; e < NE; ++e) { p[e] = expf(p[e] - m); s += p[e]; }
  const float inv = 1.f / s;
  if (lane == 0) {
#pragma unroll
    for (int e = 0; e < NE; ++e) wout[t * NE + e] = p[e] * inv;
  }
}

// ------------- expert_w [E][H][H] fp32 -> Wt [E][d][h] bf16 (transposed) -------------
__global__ __launch_bounds__(256) void wconv_kernel(
    const float* __restrict__ ew, u16* __restrict__ wt)
{
  __shared__ u16 tile[64][66];
  const int e  = blockIdx.z;
  const int h0 = blockIdx.y * 64;
  const int d0 = blockIdx.x * 64;
  const int c  = threadIdx.x & 63;
  const int r0 = threadIdx.x >> 6;
  const float* src = ew + (size_t)e * HD * HD;
  u16* dst = wt + (size_t)e * HD * HD;
#pragma unroll
  for (int i = 0; i < 16; ++i) {
    const int r = i * 4 + r0;
    tile[r][c] = f2bf(src[(size_t)(h0 + r) * HD + d0 + c]);
  }
  __syncthreads();
#pragma unroll
  for (int i = 0; i < 16; ++i) {
    const int r = i * 4 + r0;
    dst[(size_t)(d0 + r) * HD + h0 + c] = tile[c][r];
  }
}

// ------- fused dense-MoE GEMM — r5 schedule + slot-interleaved LDS (imm-offset ds_reads) -------
// out[t,d] = sum_e w[t,e] * ( sum_k A[t,k] * Wt[e][d][k] + eb[e][d] )
// LDS slot s at byte s*49152:  [A 16 KB | B 32 KB];  wgs table at 147456.
#define BM 128
#define BN 256
#define BK 64
#define SLOT 49152

#define MM(a_, b_, c_) __builtin_amdgcn_mfma_f32_16x16x32_bf16((a_), (b_), (c_), 0, 0, 0)

#define GL(srcp_, dstp_) __builtin_amdgcn_global_load_lds( \
    (const __attribute__((address_space(1))) void*)(srcp_), \
    (__attribute__((address_space(3))) void*)(dstp_), 16, 0, 0)

// staging (identical content to r5): 512 thr x 16B = 8KB/round (64 rows);
// A = 2 rounds, B = 4 rounds; dest linear, source pre-swizzled.
#define STAGE_PA(sq_)                                               \
  {                                                                 \
    const int se_ = (sq_) >> 4;                                     \
    const int sk_ = ((sq_) & 15) << 6;                              \
    const u16* as_ = aSrc0 + sk_;                                   \
    const u16* bs_ = bSrc0 + (size_t)se_ * (HD * HD) + sk_;         \
    char* ad_ = smem + stS + tid * 16;                              \
    char* bd_ = smem + stS + 16384 + tid * 16;                      \
    GL(as_,         ad_);                                           \
    GL(as_ + 65536, ad_ + 8192);                                    \
    GL(bs_,         bd_);                                           \
  }
#define STAGE_PB(sq_)                                               \
  {                                                                 \
    const int se_ = (sq_) >> 4;                                     \
    const int sk_ = ((sq_) & 15) << 6;                              \
    const u16* bs_ = bSrc0 + (size_t)se_ * (HD * HD) + sk_;         \
    char* bd_ = smem + stS + 16384 + tid * 16;                      \
    GL(bs_ +  65536, bd_ +  8192);                                  \
    GL(bs_ + 131072, bd_ + 16384);                                  \
    GL(bs_ + 196608, bd_ + 24576);                                  \
  }

// fragment reads: one VGPR base + compile-time imm offsets (rows 16 apart = +2048 B)
#define READS(aP_, bP_)                                   \
    bf8 a0 = *(const bf8*)(aP_);                          \
    bf8 a1 = *(const bf8*)((aP_) + 2048);                 \
    bf8 a2 = *(const bf8*)((aP_) + 4096);                 \
    bf8 a3 = *(const bf8*)((aP_) + 6144);                 \
    bf8 b0 = *(const bf8*)(bP_);                          \
    bf8 b1 = *(const bf8*)((bP_) + 2048);                 \
    bf8 b2 = *(const bf8*)((bP_) + 4096);                 \
    bf8 b3 = *(const bf8*)((bP_) + 6144);

#define MFMA16                                            \
    acc[0][0] = MM(a0, b0, acc[0][0]);                    \
    acc[1][0] = MM(a1, b0, acc[1][0]);                    \
    acc[2][0] = MM(a2, b0, acc[2][0]);                    \
    acc[3][0] = MM(a3, b0, acc[3][0]);                    \
    acc[0][1] = MM(a0, b1, acc[0][1]);                    \
    acc[1][1] = MM(a1, b1, acc[1][1]);                    \
    acc[2][1] = MM(a2, b1, acc[2][1]);                    \
    acc[3][1] = MM(a3, b1, acc[3][1]);                    \
    acc[0][2] = MM(a0, b2, acc[0][2]);                    \
    acc[1][2] = MM(a1, b2, acc[1][2]);                    \
    acc[2][2] = MM(a2, b2, acc[2][2]);                    \
    acc[3][2] = MM(a3, b2, acc[3][2]);                    \
    acc[0][3] = MM(a0, b3, acc[0][3]);                    \
    acc[1][3] = MM(a1, b3, acc[1][3]);                    \
    acc[2][3] = MM(a2, b3, acc[2][3]);                    \
    acc[3][3] = MM(a3, b3, acc[3][3]);

#define FOLD(e_)                                                      \
  {                                                                   \
    _Pragma("unroll")                                                 \
    for (int mi = 0; mi < 4; ++mi) {                                  \
      const int r_ = wrb + mi * 16 + lhi * 4;                         \
      const float w0 = wgs[(r_ + 0) * 9 + (e_)];                      \
      const float w1 = wgs[(r_ + 1) * 9 + (e_)];                      \
      const float w2 = wgs[(r_ + 2) * 9 + (e_)];                      \
      const float w3 = wgs[(r_ + 3) * 9 + (e_)];                      \
      _Pragma("unroll")                                               \
      for (int ni = 0; ni < 4; ++ni) {                                \
        accO[mi][ni][0] += w0 * acc[mi][ni][0];                       \
        accO[mi][ni][1] += w1 * acc[mi][ni][1];                       \
        accO[mi][ni][2] += w2 * acc[mi][ni][2];                       \
        accO[mi][ni][3] += w3 * acc[mi][ni][3];                       \
        acc[mi][ni] = fz;                                             \
      }                                                               \
    }                                                                 \
  }

#define ADVANCE                                          \
    curS += SLOT; if (curS == 3 * SLOT) curS = 0;        \
    stS  += SLOT; if (stS  == 3 * SLOT) stS  = 0;

#define BAR       __builtin_amdgcn_s_barrier();
#define LGKM0     asm volatile("s_waitcnt lgkmcnt(0)" ::: "memory");
#define PRIO1     __builtin_amdgcn_s_setprio(1);
#define PRIO0     __builtin_amdgcn_s_setprio(0);

__global__ __launch_bounds__(512, 2) void moe_gemm_kernel(
    const u16* __restrict__ A,      // [T][H] bf16
    const u16* __restrict__ Wt,     // [E][H(d)][H(k)] bf16
    const float* __restrict__ wg,   // [T][E]
    const float* __restrict__ eb,   // [E][H]
    float* __restrict__ out)        // [T][H] fp32
{
  __shared__ __attribute__((aligned(16))) char smem[3 * SLOT + 4608]; // 148.5 KB
  float* wgs = (float*)(smem + 3 * SLOT);   // 128 rows x 8 experts, stride 9

  const int bid   = blockIdx.x;
  const int xcd   = bid & 7;
  const int local = bid >> 3;                // 0..31
  const int bm    = xcd * 8 + (local >> 2);  // 64 bm, 8 consecutive per XCD
  const int bn    = local & 3;               // 4 bn
  const int row0  = bm * BM;
  const int col0  = bn * BN;

  const int tid  = threadIdx.x;
  const int lane = tid & 63;
  const int wid  = tid >> 6;
  const int wr   = wid >> 2;        // 0..1
  const int wc   = wid & 3;         // 0..3
  const int l15  = lane & 15;
  const int lhi  = lane >> 4;
  const int wrb  = wr * 64;
  const int wcb  = wc * 64;

  // per-thread LDS fragment bases (loop-invariant); kk1 = kk0 ^ 64 (granule XOR-4)
  const int gsl   = (lhi ^ (l15 & 7)) << 4;
  const int thrA0 = wrb * 128 + l15 * 128 + gsl;
  const int thrA1 = thrA0 ^ 64;
  const int thrB0 = 16384 + wcb * 128 + l15 * 128 + gsl;
  const int thrB1 = thrB0 ^ 64;

  // staging source: thread covers row (tid>>3) of each 64-row round, granule pre-swizzled
  const int row_in = tid >> 3;
  const int gsw    = (tid & 7) ^ (row_in & 7);
  const u16* aSrc0 = A  + (size_t)(row0 + row_in) * HD + gsw * 8;
  const u16* bSrc0 = Wt + (size_t)(col0 + row_in) * HD + gsw * 8;

  // gate weights -> padded LDS table (128 rows x 8, stride 9)
  {
    const int i0 = tid, i1 = tid + 512;
    const float v0 = wg[(size_t)row0 * NE + i0];
    const float v1 = wg[(size_t)row0 * NE + i1];
    wgs[(i0 >> 3) * 9 + (i0 & 7)] = v0;
    wgs[(i1 >> 3) * 9 + (i1 & 7)] = v1;
  }
  LGKM0

  const f4 fz = {0.f, 0.f, 0.f, 0.f};
  f4 acc[4][4], accO[4][4];
#pragma unroll
  for (int i = 0; i < 4; ++i)
#pragma unroll
    for (int j = 0; j < 4; ++j) { acc[i][j] = fz; accO[i][j] = fz; }

  int curS = 0;          // compute slot byte offset
  int stS  = 2 * SLOT;   // stage target slot = (q+2)%3

  // prologue: stage tiles 0 and 1 into slots 0,1 (12 loads in flight)
  {
    const int sv = stS;
    stS = 0;    STAGE_PA(0) STAGE_PB(0)
    stS = SLOT; STAGE_PA(1) STAGE_PB(1)
    stS = sv;
  }

  for (int q = 0; q < 126; ++q) {
    asm volatile("s_waitcnt vmcnt(6)" ::: "memory");   // tile q's 6 loads landed; 6 in flight
    BAR
    const char* aP0 = smem + curS + thrA0;
    const char* aP1 = smem + curS + thrA1;
    const char* bP0 = smem + curS + thrB0;
    const char* bP1 = smem + curS + thrB1;
    // ---- phase A (kk = 0) ----
    {
      READS(aP0, bP0)
      STAGE_PA(q + 2)
      BAR LGKM0 PRIO1
      MFMA16
      PRIO0 BAR
    }
    // ---- phase B (kk = 1) ----
    {
      READS(aP1, bP1)
      STAGE_PB(q + 2)
      BAR LGKM0 PRIO1
      MFMA16
      PRIO0
    }
    ADVANCE
    if ((q & 15) == 15) FOLD(q >> 4)
  }
  // q = 126: nothing new to stage
  asm volatile("s_waitcnt vmcnt(6)" ::: "memory");
  BAR
  {
    const char* aP0 = smem + curS + thrA0;
    const char* aP1 = smem + curS + thrA1;
    const char* bP0 = smem + curS + thrB0;
    const char* bP1 = smem + curS + thrB1;
    { READS(aP0, bP0) BAR LGKM0 PRIO1 MFMA16 PRIO0 BAR }
    { READS(aP1, bP1) BAR LGKM0 PRIO1 MFMA16 PRIO0 }
  }
  ADVANCE
  // q = 127: final tile, full drain
  asm volatile("s_waitcnt vmcnt(0)" ::: "memory");
  BAR
  {
    const char* aP0 = smem + curS + thrA0;
    const char* aP1 = smem + curS + thrA1;
    const char* bP0 = smem + curS + thrB0;
    const char* bP1 = smem + curS + thrB1;
    { READS(aP0, bP0) MFMA16 }
    { READS(aP1, bP1) MFMA16 }
  }
  FOLD(7)

  // epilogue: gated bias + store (C/D: col = lane&15, row = (lane>>4)*4 + reg)
  float ebv[4][8];
#pragma unroll
  for (int ni = 0; ni < 4; ++ni) {
    const int d = col0 + wcb + ni * 16 + l15;
#pragma unroll
    for (int e2 = 0; e2 < NE; ++e2) ebv[ni][e2] = eb[(size_t)e2 * HD + d];
  }
#pragma unroll
  for (int mi = 0; mi < 4; ++mi) {
    const int r_ = wrb + mi * 16 + lhi * 4;
#pragma unroll
    for (int j = 0; j < 4; ++j) {
      const int t = row0 + r_ + j;
      const float* wrow = &wgs[(r_ + j) * 9];
#pragma unroll
      for (int ni = 0; ni < 4; ++ni) {
        const float bias =
            wrow[0] * ebv[ni][0] + wrow[1] * ebv[ni][1] +
            wrow[2] * ebv[ni][2] + wrow[3] * ebv[ni][3] +
            wrow[4] * ebv[ni][4] + wrow[5] * ebv[ni][5] +
            wrow[6] * ebv[ni][6] + wrow[7] * ebv[ni][7];
        const int d = col0 + wcb + ni * 16 + l15;
        out[(size_t)t * HD + d] = accO[mi][ni][j] + bias;
      }
    }
  }
}

extern "C" void kernel_launch(void* const* d_in, const int* in_sizes, int n_in,
                              void* d_out, int out_size, void* d_ws, size_t ws_size,
                              hipStream_t stream) {
  const float* x  = (const float*)d_in[0];   // [4,2048,1024]
  const float* gw = (const float*)d_in[1];   // [1024,8]
  const float* gb = (const float*)d_in[2];   // [8]
  const float* ew = (const float*)d_in[3];   // [8,1024,1024]
  const float* eb = (const float*)d_in[4];   // [8,1024]
  float* out = (float*)d_out;                // [4,2048,1024] fp32

  char* ws = (char*)d_ws;
  u16*   abf   = (u16*)ws;                                // 16 MB bf16 x
  u16*   wt    = (u16*)(ws + (size_t)16 * 1024 * 1024);   // 16 MB bf16 Wt
  float* wgate = (float*)(ws + (size_t)32 * 1024 * 1024); // 256 KB gate weights

  gate_conv_kernel<<<dim3(TTOK / 4), dim3(256), 0, stream>>>(x, gw, gb, wgate, abf);
  wconv_kernel<<<dim3(16, 16, 8), dim3(256), 0, stream>>>(ew, wt);
  moe_gemm_kernel<<<dim3((TTOK / BM) * (HD / BN)), dim3(512), 0, stream>>>(abf, wt, wgate, eb, out);
}

// Round 11
// 140.245 us; speedup vs baseline: 1.3454x; 1.1013x over previous
//
#include <hip/hip_runtime.h>
#include <stdint.h>

typedef unsigned short u16;
typedef short bf8 __attribute__((ext_vector_type(8)));   // 8 bf16 (bit pattern)
typedef float f4 __attribute__((ext_vector_type(4)));
typedef _Float16 h2 __attribute__((ext_vector_type(2))); // packed f16 pair

#define TTOK 8192
#define HD   1024
#define NE   8
#define HH   (HD * HD)

static __device__ __forceinline__ u16 f2bf(float f) {
  union { float f; uint32_t u; } v; v.f = f;
  return (u16)((v.u + 0x7fffu + ((v.u >> 16) & 1u)) >> 16);   // RNE
}

// ---------------- gating (fp32) + x -> bf16 conversion ----------------
__global__ __launch_bounds__(256) void gate_conv_kernel(
    const float* __restrict__ x, const float* __restrict__ gw,
    const float* __restrict__ gb, float* __restrict__ wout,
    u16* __restrict__ abf)
{
  const int t    = blockIdx.x * 4 + (threadIdx.x >> 6);
  const int lane = threadIdx.x & 63;
  const float* xr = x + (size_t)t * HD;
  float p[NE];
#pragma unroll
  for (int e = 0; e < NE; ++e) p[e] = 0.f;
#pragma unroll 4
  for (int h = lane; h < HD; h += 64) {
    const float xv = xr[h];
    abf[(size_t)t * HD + h] = f2bf(xv);
    const float* g = gw + (size_t)h * NE;
#pragma unroll
    for (int e = 0; e < NE; ++e) p[e] += xv * g[e];
  }
#pragma unroll
  for (int e = 0; e < NE; ++e) {
#pragma unroll
    for (int off = 32; off > 0; off >>= 1)
      p[e] += __shfl_xor(p[e], off, 64);
    p[e] += gb[e];
  }
  float m = p[0];
#pragma unroll
  for (int e = 1; e < NE; ++e) m = fmaxf(m, p[e]);
  float s = 0.f;
#pragma unroll
  for (int e = 0; e < NE; ++e) { p[e] = expf(p[e] - m); s += p[e]; }
  const float inv = 1.f / s;
  if (lane == 0) {
#pragma unroll
    for (int e = 0; e < NE; ++e) wout[t * NE + e] = p[e] * inv;
  }
}

// ------------- expert_w [E][H][H] fp32 -> Wt [E][d][h] bf16 (transposed) -------------
__global__ __launch_bounds__(256) void wconv_kernel(
    const float* __restrict__ ew, u16* __restrict__ wt)
{
  __shared__ u16 tile[64][66];
  const int e  = blockIdx.z;
  const int h0 = blockIdx.y * 64;
  const int d0 = blockIdx.x * 64;
  const int c  = threadIdx.x & 63;
  const int r0 = threadIdx.x >> 6;
  const float* src = ew + (size_t)e * HH;
  u16* dst = wt + (size_t)e * HH;
#pragma unroll
  for (int i = 0; i < 16; ++i) {
    const int r = i * 4 + r0;
    tile[r][c] = f2bf(src[(size_t)(h0 + r) * HD + d0 + c]);
  }
  __syncthreads();
#pragma unroll
  for (int i = 0; i < 16; ++i) {
    const int r = i * 4 + r0;
    dst[(size_t)(d0 + r) * HD + h0 + c] = tile[c][r];
  }
}

// --- fused dense-MoE GEMM — expert-PAIR wave tiles (64x64x2e), r5 schedule, f16 accO ---
// out[t,d] = sum_e w[t,e] * ( sum_k A[t,k] * Wt[e][d][k] + eb[e][d] )
// LDS slot (64 KB): [A 256x64 | B_e0 128x64 | B_e1 128x64]; ring-2; wgs at 131072.
#define BM 256
#define BN 128
#define BK 64
#define SLOT 65536

#define MM(a_, b_, c_) __builtin_amdgcn_mfma_f32_16x16x32_bf16((a_), (b_), (c_), 0, 0, 0)

#define GL(srcp_, dstp_) __builtin_amdgcn_global_load_lds( \
    (const __attribute__((address_space(1))) void*)(srcp_), \
    (__attribute__((address_space(3))) void*)(dstp_), 16, 0, 0)

// staging: 512 thr x 16B = 8 KB/round = 64 rows; A = 4 rounds, B = 2 rounds x 2 experts
#define STAGE_A(sq_)                                                \
  {                                                                 \
    const int sk_ = ((sq_) & 15) << 6;                              \
    const u16* as_ = aSrc0 + sk_;                                   \
    char* ad_ = smem + stS + tid * 16;                              \
    GL(as_,          ad_);                                          \
    GL(as_ +  65536, ad_ +  8192);                                  \
    GL(as_ + 131072, ad_ + 16384);                                  \
    GL(as_ + 196608, ad_ + 24576);                                  \
  }
#define STAGE_B(sq_)                                                \
  {                                                                 \
    const int pn_ = (sq_) >> 4;                                     \
    const int sk_ = ((sq_) & 15) << 6;                              \
    const u16* b0_ = bSrc0 + (size_t)(2 * pn_) * HH + sk_;          \
    char* bd_ = smem + stS + 32768 + tid * 16;                      \
    GL(b0_,          bd_);                                          \
    GL(b0_ +  65536, bd_ +  8192);                                  \
    GL(b0_ + HH,          bd_ + 16384);                             \
    GL(b0_ + HH + 65536,  bd_ + 24576);                             \
  }

// 12 reads: 4 A-frags + 8 B-frags (two experts) from one B base via imm offsets
#define READS(aP_, bP_)                                   \
    bf8 a0  = *(const bf8*)(aP_);                         \
    bf8 a1  = *(const bf8*)((aP_) + 2048);                \
    bf8 a2  = *(const bf8*)((aP_) + 4096);                \
    bf8 a3  = *(const bf8*)((aP_) + 6144);                \
    bf8 b00 = *(const bf8*)(bP_);                         \
    bf8 b01 = *(const bf8*)((bP_) + 2048);                \
    bf8 b02 = *(const bf8*)((bP_) + 4096);                \
    bf8 b03 = *(const bf8*)((bP_) + 6144);                \
    bf8 b10 = *(const bf8*)((bP_) + 16384);               \
    bf8 b11 = *(const bf8*)((bP_) + 18432);               \
    bf8 b12 = *(const bf8*)((bP_) + 20480);               \
    bf8 b13 = *(const bf8*)((bP_) + 22528);

#define MFMA32                                            \
    acc0[0][0] = MM(a0, b00, acc0[0][0]);                 \
    acc0[1][0] = MM(a1, b00, acc0[1][0]);                 \
    acc0[2][0] = MM(a2, b00, acc0[2][0]);                 \
    acc0[3][0] = MM(a3, b00, acc0[3][0]);                 \
    acc0[0][1] = MM(a0, b01, acc0[0][1]);                 \
    acc0[1][1] = MM(a1, b01, acc0[1][1]);                 \
    acc0[2][1] = MM(a2, b01, acc0[2][1]);                 \
    acc0[3][1] = MM(a3, b01, acc0[3][1]);                 \
    acc0[0][2] = MM(a0, b02, acc0[0][2]);                 \
    acc0[1][2] = MM(a1, b02, acc0[1][2]);                 \
    acc0[2][2] = MM(a2, b02, acc0[2][2]);                 \
    acc0[3][2] = MM(a3, b02, acc0[3][2]);                 \
    acc0[0][3] = MM(a0, b03, acc0[0][3]);                 \
    acc0[1][3] = MM(a1, b03, acc0[1][3]);                 \
    acc0[2][3] = MM(a2, b03, acc0[2][3]);                 \
    acc0[3][3] = MM(a3, b03, acc0[3][3]);                 \
    acc1[0][0] = MM(a0, b10, acc1[0][0]);                 \
    acc1[1][0] = MM(a1, b10, acc1[1][0]);                 \
    acc1[2][0] = MM(a2, b10, acc1[2][0]);                 \
    acc1[3][0] = MM(a3, b10, acc1[3][0]);                 \
    acc1[0][1] = MM(a0, b11, acc1[0][1]);                 \
    acc1[1][1] = MM(a1, b11, acc1[1][1]);                 \
    acc1[2][1] = MM(a2, b11, acc1[2][1]);                 \
    acc1[3][1] = MM(a3, b11, acc1[3][1]);                 \
    acc1[0][2] = MM(a0, b12, acc1[0][2]);                 \
    acc1[1][2] = MM(a1, b12, acc1[1][2]);                 \
    acc1[2][2] = MM(a2, b12, acc1[2][2]);                 \
    acc1[3][2] = MM(a3, b12, acc1[3][2]);                 \
    acc1[0][3] = MM(a0, b13, acc1[0][3]);                 \
    acc1[1][3] = MM(a1, b13, acc1[1][3]);                 \
    acc1[2][3] = MM(a2, b13, acc1[2][3]);                 \
    acc1[3][3] = MM(a3, b13, acc1[3][3]);

// fold expert pair (e0_, e1_) into packed-f16 accO; zero acc0/acc1
#define FOLD(e0_, e1_)                                                  \
  {                                                                     \
    _Pragma("unroll")                                                   \
    for (int mi = 0; mi < 4; ++mi) {                                    \
      const int r_ = wrb + mi * 16 + lhi * 4;                           \
      float wa[4], wb[4];                                               \
      _Pragma("unroll")                                                 \
      for (int j = 0; j < 4; ++j) {                                     \
        wa[j] = wgs[(r_ + j) * 9 + (e0_)];                              \
        wb[j] = wgs[(r_ + j) * 9 + (e1_)];                              \
      }                                                                 \
      _Pragma("unroll")                                                 \
      for (int ni = 0; ni < 4; ++ni) {                                  \
        const float f0 = wa[0] * acc0[mi][ni][0] + wb[0] * acc1[mi][ni][0]; \
        const float f1 = wa[1] * acc0[mi][ni][1] + wb[1] * acc1[mi][ni][1]; \
        const float f2 = wa[2] * acc0[mi][ni][2] + wb[2] * acc1[mi][ni][2]; \
        const float f3 = wa[3] * acc0[mi][ni][3] + wb[3] * acc1[mi][ni][3]; \
        h2 t0; t0[0] = (_Float16)f0; t0[1] = (_Float16)f1;              \
        h2 t1; t1[0] = (_Float16)f2; t1[1] = (_Float16)f3;              \
        accP0[mi][ni] += t0;                                            \
        accP1[mi][ni] += t1;                                            \
        acc0[mi][ni] = fz; acc1[mi][ni] = fz;                           \
      }                                                                 \
    }                                                                   \
  }

#define BAR       __builtin_amdgcn_s_barrier();
#define LGKM0     asm volatile("s_waitcnt lgkmcnt(0)" ::: "memory");
#define VM0       asm volatile("s_waitcnt vmcnt(0)" ::: "memory");
#define PRIO1     __builtin_amdgcn_s_setprio(1);
#define PRIO0     __builtin_amdgcn_s_setprio(0);

__global__ __launch_bounds__(512, 2) void moe_gemm_kernel(
    const u16* __restrict__ A,      // [T][H] bf16
    const u16* __restrict__ Wt,     // [E][H(d)][H(k)] bf16
    const float* __restrict__ wg,   // [T][E]
    const float* __restrict__ eb,   // [E][H]
    float* __restrict__ out)        // [T][H] fp32
{
  __shared__ __attribute__((aligned(16))) char smem[2 * SLOT + 9216]; // 140.3 KB
  float* wgs = (float*)(smem + 2 * SLOT);   // 256 rows x 8 experts, stride 9

  const int bid   = blockIdx.x;
  const int xcd   = bid & 7;
  const int local = bid >> 3;                // 0..31
  const int bm    = xcd * 4 + (local & 3);   // 32 bm, 4 per XCD
  const int bn    = local >> 2;              // 8 bn
  const int row0  = bm * BM;
  const int col0  = bn * BN;

  const int tid  = threadIdx.x;
  const int lane = tid & 63;
  const int wid  = tid >> 6;
  const int wr   = wid >> 1;        // 0..3  (64-row band)
  const int wc   = wid & 1;         // 0..1  (64-col band)
  const int l15  = lane & 15;
  const int lhi  = lane >> 4;
  const int wrb  = wr * 64;
  const int wcb  = wc * 64;

  // per-thread LDS fragment bases; kk1 = kk0 ^ 64 (granule XOR-4)
  const int gsl   = (lhi ^ (l15 & 7)) << 4;
  const int thrA0 = wrb * 128 + l15 * 128 + gsl;
  const int thrA1 = thrA0 ^ 64;
  const int thrB0 = 32768 + wcb * 128 + l15 * 128 + gsl;
  const int thrB1 = thrB0 ^ 64;

  // staging source: thread covers row (tid>>3) of each 64-row round, pre-swizzled granule
  const int row_in = tid >> 3;
  const int gsw    = (tid & 7) ^ (row_in & 7);
  const u16* aSrc0 = A  + (size_t)(row0 + row_in) * HD + gsw * 8;
  const u16* bSrc0 = Wt + (size_t)(col0 + row_in) * HD + gsw * 8;

  // gate weights -> padded LDS table (256 rows x 8, stride 9)
  {
    const f4 v = *(const f4*)(wg + (size_t)row0 * NE + tid * 4);
    const int i0 = tid * 4;
#pragma unroll
    for (int k = 0; k < 4; ++k) {
      const int idx = i0 + k;
      wgs[(idx >> 3) * 9 + (idx & 7)] = v[k];
    }
  }
  LGKM0

  const f4 fz = {0.f, 0.f, 0.f, 0.f};
  const h2 hz = {(_Float16)0.f, (_Float16)0.f};
  f4 acc0[4][4], acc1[4][4];
  h2 accP0[4][4], accP1[4][4];
#pragma unroll
  for (int i = 0; i < 4; ++i)
#pragma unroll
    for (int j = 0; j < 4; ++j) {
      acc0[i][j] = fz; acc1[i][j] = fz;
      accP0[i][j] = hz; accP1[i][j] = hz;
    }

  int curS = 0, stS = SLOT;

  // prologue: stage tile 0 (pair 0, kcol 0) into slot 0
  { const int sv = stS; stS = 0; STAGE_A(0) STAGE_B(0) stS = sv; }

  for (int q = 0; q < 63; ++q) {
    VM0                               // tile q landed (issued >= half-iter ago)
    BAR
    const char* aP0 = smem + curS + thrA0;
    const char* aP1 = smem + curS + thrA1;
    const char* bP0 = smem + curS + thrB0;
    const char* bP1 = smem + curS + thrB1;
    // ---- phase A (kk = 0) ----
    {
      READS(aP0, bP0)
      STAGE_A(q + 1)
      BAR LGKM0 PRIO1
      MFMA32
      PRIO0 BAR
    }
    // ---- phase B (kk = 1) ----
    {
      READS(aP1, bP1)
      STAGE_B(q + 1)
      BAR LGKM0 PRIO1
      MFMA32
      PRIO0
    }
    { const int t_ = curS; curS = stS; stS = t_; }
    if ((q & 15) == 15) { const int p_ = q >> 4; FOLD(2 * p_, 2 * p_ + 1) }
  }
  // q = 63: final tile, full drain, no staging
  VM0
  BAR
  {
    const char* aP0 = smem + curS + thrA0;
    const char* aP1 = smem + curS + thrA1;
    const char* bP0 = smem + curS + thrB0;
    const char* bP1 = smem + curS + thrB1;
    { READS(aP0, bP0) BAR LGKM0 PRIO1 MFMA32 PRIO0 BAR }
    { READS(aP1, bP1) BAR LGKM0 PRIO1 MFMA32 PRIO0 }
  }
  FOLD(6, 7)

  // epilogue: unpack f16 accO + gated bias (fp32) + store
  float ebv[4][8];
#pragma unroll
  for (int ni = 0; ni < 4; ++ni) {
    const int d = col0 + wcb + ni * 16 + l15;
#pragma unroll
    for (int e2 = 0; e2 < NE; ++e2) ebv[ni][e2] = eb[(size_t)e2 * HD + d];
  }
#pragma unroll
  for (int mi = 0; mi < 4; ++mi) {
    const int r_ = wrb + mi * 16 + lhi * 4;
#pragma unroll
    for (int j = 0; j < 4; ++j) {
      const int t = row0 + r_ + j;
      const float* wrow = &wgs[(r_ + j) * 9];
#pragma unroll
      for (int ni = 0; ni < 4; ++ni) {
        const float bias =
            wrow[0] * ebv[ni][0] + wrow[1] * ebv[ni][1] +
            wrow[2] * ebv[ni][2] + wrow[3] * ebv[ni][3] +
            wrow[4] * ebv[ni][4] + wrow[5] * ebv[ni][5] +
            wrow[6] * ebv[ni][6] + wrow[7] * ebv[ni][7];
        const float v = (j < 2) ? (float)accP0[mi][ni][j & 1]
                                : (float)accP1[mi][ni][j & 1];
        const int d = col0 + wcb + ni * 16 + l15;
        out[(size_t)t * HD + d] = v + bias;
      }
    }
  }
}

extern "C" void kernel_launch(void* const* d_in, const int* in_sizes, int n_in,
                              void* d_out, int out_size, void* d_ws, size_t ws_size,
                              hipStream_t stream) {
  const float* x  = (const float*)d_in[0];   // [4,2048,1024]
  const float* gw = (const float*)d_in[1];   // [1024,8]
  const float* gb = (const float*)d_in[2];   // [8]
  const float* ew = (const float*)d_in[3];   // [8,1024,1024]
  const float* eb = (const float*)d_in[4];   // [8,1024]
  float* out = (float*)d_out;                // [4,2048,1024] fp32

  char* ws = (char*)d_ws;
  u16*   abf   = (u16*)ws;                                // 16 MB bf16 x
  u16*   wt    = (u16*)(ws + (size_t)16 * 1024 * 1024);   // 16 MB bf16 Wt
  float* wgate = (float*)(ws + (size_t)32 * 1024 * 1024); // 256 KB gate weights

  gate_conv_kernel<<<dim3(TTOK / 4), dim3(256), 0, stream>>>(x, gw, gb, wgate, abf);
  wconv_kernel<<<dim3(16, 16, 8), dim3(256), 0, stream>>>(ew, wt);
  moe_gemm_kernel<<<dim3((TTOK / BM) * (HD / BN)), dim3(512), 0, stream>>>(abf, wt, wgate, eb, out);
}

// Round 12
// 135.405 us; speedup vs baseline: 1.3935x; 1.0357x over previous
//
#include <hip/hip_runtime.h>
#include <stdint.h>

typedef unsigned short u16;
typedef short bf8 __attribute__((ext_vector_type(8)));   // 8 bf16 (bit pattern)
typedef float f4 __attribute__((ext_vector_type(4)));
typedef _Float16 h2 __attribute__((ext_vector_type(2))); // packed f16 pair

#define TTOK 8192
#define HD   1024
#define NE   8
#define HH   (HD * HD)

static __device__ __forceinline__ u16 f2bf(float f) {
  union { float f; uint32_t u; } v; v.f = f;
  return (u16)((v.u + 0x7fffu + ((v.u >> 16) & 1u)) >> 16);   // RNE
}

// ---------------- gating (fp32) + x -> bf16 conversion ----------------
__global__ __launch_bounds__(256) void gate_conv_kernel(
    const float* __restrict__ x, const float* __restrict__ gw,
    const float* __restrict__ gb, float* __restrict__ wout,
    u16* __restrict__ abf)
{
  const int t    = blockIdx.x * 4 + (threadIdx.x >> 6);
  const int lane = threadIdx.x & 63;
  const float* xr = x + (size_t)t * HD;
  float p[NE];
#pragma unroll
  for (int e = 0; e < NE; ++e) p[e] = 0.f;
#pragma unroll 4
  for (int h = lane; h < HD; h += 64) {
    const float xv = xr[h];
    abf[(size_t)t * HD + h] = f2bf(xv);
    const float* g = gw + (size_t)h * NE;
#pragma unroll
    for (int e = 0; e < NE; ++e) p[e] += xv * g[e];
  }
#pragma unroll
  for (int e = 0; e < NE; ++e) {
#pragma unroll
    for (int off = 32; off > 0; off >>= 1)
      p[e] += __shfl_xor(p[e], off, 64);
    p[e] += gb[e];
  }
  float m = p[0];
#pragma unroll
  for (int e = 1; e < NE; ++e) m = fmaxf(m, p[e]);
  float s = 0.f;
#pragma unroll
  for (int e = 0; e < NE; ++e) { p[e] = expf(p[e] - m); s += p[e]; }
  const float inv = 1.f / s;
  if (lane == 0) {
#pragma unroll
    for (int e = 0; e < NE; ++e) wout[t * NE + e] = p[e] * inv;
  }
}

// ------------- expert_w [E][H][H] fp32 -> Wt [E][d][h] bf16 (transposed) -------------
__global__ __launch_bounds__(256) void wconv_kernel(
    const float* __restrict__ ew, u16* __restrict__ wt)
{
  __shared__ u16 tile[64][66];
  const int e  = blockIdx.z;
  const int h0 = blockIdx.y * 64;
  const int d0 = blockIdx.x * 64;
  const int c  = threadIdx.x & 63;
  const int r0 = threadIdx.x >> 6;
  const float* src = ew + (size_t)e * HH;
  u16* dst = wt + (size_t)e * HH;
#pragma unroll
  for (int i = 0; i < 16; ++i) {
    const int r = i * 4 + r0;
    tile[r][c] = f2bf(src[(size_t)(h0 + r) * HD + d0 + c]);
  }
  __syncthreads();
#pragma unroll
  for (int i = 0; i < 16; ++i) {
    const int r = i * 4 + r0;
    dst[(size_t)(d0 + r) * HD + h0 + c] = tile[c][r];
  }
}

// --- fused dense-MoE GEMM — expert-pair tiles + counted-lgkm interleave (AITER-style) ---
// out[t,d] = sum_e w[t,e] * ( sum_k A[t,k] * Wt[e][d][k] + eb[e][d] )
// LDS slot (64 KB): [A 256x64 | B_e0 128x64 | B_e1 128x64]; ring-2; wgs at 131072.
#define BM 256
#define BN 128
#define BK 64
#define SLOT 65536

#define MM(a_, b_, c_) __builtin_amdgcn_mfma_f32_16x16x32_bf16((a_), (b_), (c_), 0, 0, 0)

#define GL(srcp_, dstp_) __builtin_amdgcn_global_load_lds( \
    (const __attribute__((address_space(1))) void*)(srcp_), \
    (__attribute__((address_space(3))) void*)(dstp_), 16, 0, 0)

#define STAGE_A(sq_)                                                \
  {                                                                 \
    const int sk_ = ((sq_) & 15) << 6;                              \
    const u16* as_ = aSrc0 + sk_;                                   \
    char* ad_ = smem + stS + tid * 16;                              \
    GL(as_,          ad_);                                          \
    GL(as_ +  65536, ad_ +  8192);                                  \
    GL(as_ + 131072, ad_ + 16384);                                  \
    GL(as_ + 196608, ad_ + 24576);                                  \
  }
#define STAGE_B(sq_)                                                \
  {                                                                 \
    const int pn_ = (sq_) >> 4;                                     \
    const int sk_ = ((sq_) & 15) << 6;                              \
    const u16* b0_ = bSrc0 + (size_t)(2 * pn_) * HH + sk_;          \
    char* bd_ = smem + stS + 32768 + tid * 16;                      \
    GL(b0_,          bd_);                                          \
    GL(b0_ +  65536, bd_ +  8192);                                  \
    GL(b0_ + HH,          bd_ + 16384);                             \
    GL(b0_ + HH + 65536,  bd_ + 24576);                             \
  }

// one 16-MFMA cluster: acc_[0..3][0..3] += a_i x b_j
#define MFMA16E(ACC_, A0_, A1_, A2_, A3_, B0_, B1_, B2_, B3_)  \
    ACC_[0][0] = MM(A0_, B0_, ACC_[0][0]);                     \
    ACC_[1][0] = MM(A1_, B0_, ACC_[1][0]);                     \
    ACC_[2][0] = MM(A2_, B0_, ACC_[2][0]);                     \
    ACC_[3][0] = MM(A3_, B0_, ACC_[3][0]);                     \
    ACC_[0][1] = MM(A0_, B1_, ACC_[0][1]);                     \
    ACC_[1][1] = MM(A1_, B1_, ACC_[1][1]);                     \
    ACC_[2][1] = MM(A2_, B1_, ACC_[2][1]);                     \
    ACC_[3][1] = MM(A3_, B1_, ACC_[3][1]);                     \
    ACC_[0][2] = MM(A0_, B2_, ACC_[0][2]);                     \
    ACC_[1][2] = MM(A1_, B2_, ACC_[1][2]);                     \
    ACC_[2][2] = MM(A2_, B2_, ACC_[2][2]);                     \
    ACC_[3][2] = MM(A3_, B2_, ACC_[3][2]);                     \
    ACC_[0][3] = MM(A0_, B3_, ACC_[0][3]);                     \
    ACC_[1][3] = MM(A1_, B3_, ACC_[1][3]);                     \
    ACC_[2][3] = MM(A3 == A3 ? A3_ : A3_, B3_, ACC_[2][3]);    \
    ACC_[3][3] = MM(A3_, B3_, ACC_[3][3]);

// (typo-proof version without the ternary)
#undef MFMA16E
#define MFMA16E(ACC_, A0_, A1_, A2_, A3_, B0_, B1_, B2_, B3_)  \
    ACC_[0][0] = MM(A0_, B0_, ACC_[0][0]);                     \
    ACC_[1][0] = MM(A1_, B0_, ACC_[1][0]);                     \
    ACC_[2][0] = MM(A2_, B0_, ACC_[2][0]);                     \
    ACC_[3][0] = MM(A3_, B0_, ACC_[3][0]);                     \
    ACC_[0][1] = MM(A0_, B1_, ACC_[0][1]);                     \
    ACC_[1][1] = MM(A1_, B1_, ACC_[1][1]);                     \
    ACC_[2][1] = MM(A2_, B1_, ACC_[2][1]);                     \
    ACC_[3][1] = MM(A3_, B1_, ACC_[3][1]);                     \
    ACC_[0][2] = MM(A0_, B2_, ACC_[0][2]);                     \
    ACC_[1][2] = MM(A1_, B2_, ACC_[1][2]);                     \
    ACC_[2][2] = MM(A2_, B2_, ACC_[2][2]);                     \
    ACC_[3][2] = MM(A3_, B2_, ACC_[3][2]);                     \
    ACC_[0][3] = MM(A0_, B3_, ACC_[0][3]);                     \
    ACC_[1][3] = MM(A1_, B3_, ACC_[1][3]);                     \
    ACC_[2][3] = MM(A2_, B3_, ACC_[2][3]);                     \
    ACC_[3][3] = MM(A3_, B3_, ACC_[3][3]);

#define FOLD(e0_, e1_)                                                  \
  {                                                                     \
    _Pragma("unroll")                                                   \
    for (int mi = 0; mi < 4; ++mi) {                                    \
      const int r_ = wrb + mi * 16 + lhi * 4;                           \
      float wa[4], wb[4];                                               \
      _Pragma("unroll")                                                 \
      for (int j = 0; j < 4; ++j) {                                     \
        wa[j] = wgs[(r_ + j) * 9 + (e0_)];                              \
        wb[j] = wgs[(r_ + j) * 9 + (e1_)];                              \
      }                                                                 \
      _Pragma("unroll")                                                 \
      for (int ni = 0; ni < 4; ++ni) {                                  \
        const float f0 = wa[0] * acc0[mi][ni][0] + wb[0] * acc1[mi][ni][0]; \
        const float f1 = wa[1] * acc0[mi][ni][1] + wb[1] * acc1[mi][ni][1]; \
        const float f2 = wa[2] * acc0[mi][ni][2] + wb[2] * acc1[mi][ni][2]; \
        const float f3 = wa[3] * acc0[mi][ni][3] + wb[3] * acc1[mi][ni][3]; \
        h2 t0; t0[0] = (_Float16)f0; t0[1] = (_Float16)f1;              \
        h2 t1; t1[0] = (_Float16)f2; t1[1] = (_Float16)f3;              \
        accP0[mi][ni] += t0;                                            \
        accP1[mi][ni] += t1;                                            \
        acc0[mi][ni] = fz; acc1[mi][ni] = fz;                           \
      }                                                                 \
    }                                                                   \
  }

#define BAR       __builtin_amdgcn_s_barrier();
#define VM0       asm volatile("s_waitcnt vmcnt(0)" ::: "memory");
#define LGKM(n_)  asm volatile("s_waitcnt lgkmcnt(" #n_ ")" ::: "memory");
#define SCHED0    __builtin_amdgcn_sched_barrier(0);
#define PRIO1     __builtin_amdgcn_s_setprio(1);
#define PRIO0     __builtin_amdgcn_s_setprio(0);

// tile body: 4 read-groups interleaved with 4 MFMA clusters via counted lgkm
#define TILE_BODY(DO_STAGE_, sq_)                                        \
  {                                                                      \
    const char* aP0 = smem + curS + thrA0;                               \
    const char* aP1 = smem + curS + thrA1;                               \
    const char* bP0 = smem + curS + thrB0;                               \
    const char* bP1 = smem + curS + thrB1;                               \
    /* g1: A kk0 (4) + B e0 kk0 (4) */                                   \
    bf8 a00 = *(const bf8*)(aP0);                                        \
    bf8 a01 = *(const bf8*)(aP0 + 2048);                                 \
    bf8 a02 = *(const bf8*)(aP0 + 4096);                                 \
    bf8 a03 = *(const bf8*)(aP0 + 6144);                                 \
    bf8 b000 = *(const bf8*)(bP0);                                       \
    bf8 b001 = *(const bf8*)(bP0 + 2048);                                \
    bf8 b002 = *(const bf8*)(bP0 + 4096);                                \
    bf8 b003 = *(const bf8*)(bP0 + 6144);                                \
    /* g2: B e1 kk0 (4) — lands during cluster 1 */                      \
    bf8 b100 = *(const bf8*)(bP0 + 16384);                               \
    bf8 b101 = *(const bf8*)(bP0 + 18432);                               \
    bf8 b102 = *(const bf8*)(bP0 + 20480);                               \
    bf8 b103 = *(const bf8*)(bP0 + 22528);                               \
    if (DO_STAGE_) STAGE_A(sq_)                                          \
    LGKM(4) SCHED0                                                       \
    PRIO1 MFMA16E(acc0, a00, a01, a02, a03, b000, b001, b002, b003)      \
    PRIO0 SCHED0                                                         \
    /* g3: A kk1 (4) + B e0 kk1 (4) — lands during cluster 2 */          \
    bf8 a10 = *(const bf8*)(aP1);                                        \
    bf8 a11 = *(const bf8*)(aP1 + 2048);                                 \
    bf8 a12 = *(const bf8*)(aP1 + 4096);                                 \
    bf8 a13 = *(const bf8*)(aP1 + 6144);                                 \
    bf8 b010 = *(const bf8*)(bP1);                                       \
    bf8 b011 = *(const bf8*)(bP1 + 2048);                                \
    bf8 b012 = *(const bf8*)(bP1 + 4096);                                \
    bf8 b013 = *(const bf8*)(bP1 + 6144);                                \
    LGKM(8) SCHED0                                                       \
    PRIO1 MFMA16E(acc1, a00, a01, a02, a03, b100, b101, b102, b103)      \
    PRIO0 SCHED0                                                         \
    if (DO_STAGE_) STAGE_B(sq_)                                          \
    /* g4: B e1 kk1 (4) — lands during cluster 3 */                      \
    bf8 b110 = *(const bf8*)(bP1 + 16384);                               \
    bf8 b111 = *(const bf8*)(bP1 + 18432);                               \
    bf8 b112 = *(const bf8*)(bP1 + 20480);                               \
    bf8 b113 = *(const bf8*)(bP1 + 22528);                               \
    LGKM(4) SCHED0                                                       \
    PRIO1 MFMA16E(acc0, a10, a11, a12, a13, b010, b011, b012, b013)      \
    PRIO0 SCHED0                                                         \
    LGKM(0) SCHED0                                                       \
    PRIO1 MFMA16E(acc1, a10, a11, a12, a13, b110, b111, b112, b113)      \
    PRIO0 SCHED0                                                         \
  }

__global__ __launch_bounds__(512, 2) void moe_gemm_kernel(
    const u16* __restrict__ A,      // [T][H] bf16
    const u16* __restrict__ Wt,     // [E][H(d)][H(k)] bf16
    const float* __restrict__ wg,   // [T][E]
    const float* __restrict__ eb,   // [E][H]
    float* __restrict__ out)        // [T][H] fp32
{
  __shared__ __attribute__((aligned(16))) char smem[2 * SLOT + 9216]; // 140.3 KB
  float* wgs = (float*)(smem + 2 * SLOT);   // 256 rows x 8 experts, stride 9

  const int bid   = blockIdx.x;
  const int xcd   = bid & 7;
  const int local = bid >> 3;                // 0..31
  const int bm    = xcd * 4 + (local & 3);   // 32 bm, 4 per XCD
  const int bn    = local >> 2;              // 8 bn
  const int row0  = bm * BM;
  const int col0  = bn * BN;

  const int tid  = threadIdx.x;
  const int lane = tid & 63;
  const int wid  = tid >> 6;
  const int wr   = wid >> 1;        // 0..3  (64-row band)
  const int wc   = wid & 1;         // 0..1  (64-col band)
  const int l15  = lane & 15;
  const int lhi  = lane >> 4;
  const int wrb  = wr * 64;
  const int wcb  = wc * 64;

  // per-thread LDS fragment bases; kk1 = kk0 ^ 64 (granule XOR-4)
  const int gsl   = (lhi ^ (l15 & 7)) << 4;
  const int thrA0 = wrb * 128 + l15 * 128 + gsl;
  const int thrA1 = thrA0 ^ 64;
  const int thrB0 = 32768 + wcb * 128 + l15 * 128 + gsl;
  const int thrB1 = thrB0 ^ 64;

  // staging source: thread covers row (tid>>3) of each 64-row round, pre-swizzled granule
  const int row_in = tid >> 3;
  const int gsw    = (tid & 7) ^ (row_in & 7);
  const u16* aSrc0 = A  + (size_t)(row0 + row_in) * HD + gsw * 8;
  const u16* bSrc0 = Wt + (size_t)(col0 + row_in) * HD + gsw * 8;

  // gate weights -> padded LDS table (256 rows x 8, stride 9)
  {
    const f4 v = *(const f4*)(wg + (size_t)row0 * NE + tid * 4);
    const int i0 = tid * 4;
#pragma unroll
    for (int k = 0; k < 4; ++k) {
      const int idx = i0 + k;
      wgs[(idx >> 3) * 9 + (idx & 7)] = v[k];
    }
  }
  LGKM(0)

  const f4 fz = {0.f, 0.f, 0.f, 0.f};
  const h2 hz = {(_Float16)0.f, (_Float16)0.f};
  f4 acc0[4][4], acc1[4][4];
  h2 accP0[4][4], accP1[4][4];
#pragma unroll
  for (int i = 0; i < 4; ++i)
#pragma unroll
    for (int j = 0; j < 4; ++j) {
      acc0[i][j] = fz; acc1[i][j] = fz;
      accP0[i][j] = hz; accP1[i][j] = hz;
    }

  int curS = 0, stS = SLOT;

  // prologue: stage tile 0 (pair 0, kcol 0) into slot 0
  { const int sv = stS; stS = 0; STAGE_A(0) STAGE_B(0) stS = sv; }

  for (int q = 0; q < 63; ++q) {
    VM0                               // tile q landed (issued a full tile ago)
    BAR
    TILE_BODY(1, q + 1)
    { const int t_ = curS; curS = stS; stS = t_; }
    if ((q & 15) == 15) { const int p_ = q >> 4; FOLD(2 * p_, 2 * p_ + 1) }
  }
  // q = 63: final tile, full drain, no staging
  VM0
  BAR
  TILE_BODY(0, 0)
  FOLD(6, 7)

  // epilogue: unpack f16 accO + gated bias (fp32) + store
  float ebv[4][8];
#pragma unroll
  for (int ni = 0; ni < 4; ++ni) {
    const int d = col0 + wcb + ni * 16 + l15;
#pragma unroll
    for (int e2 = 0; e2 < NE; ++e2) ebv[ni][e2] = eb[(size_t)e2 * HD + d];
  }
#pragma unroll
  for (int mi = 0; mi < 4; ++mi) {
    const int r_ = wrb + mi * 16 + lhi * 4;
#pragma unroll
    for (int j = 0; j < 4; ++j) {
      const int t = row0 + r_ + j;
      const float* wrow = &wgs[(r_ + j) * 9];
#pragma unroll
      for (int ni = 0; ni < 4; ++ni) {
        const float bias =
            wrow[0] * ebv[ni][0] + wrow[1] * ebv[ni][1] +
            wrow[2] * ebv[ni][2] + wrow[3] * ebv[ni][3] +
            wrow[4] * ebv[ni][4] + wrow[5] * ebv[ni][5] +
            wrow[6] * ebv[ni][6] + wrow[7] * ebv[ni][7];
        const float v = (j < 2) ? (float)accP0[mi][ni][j & 1]
                                : (float)accP1[mi][ni][j & 1];
        const int d = col0 + wcb + ni * 16 + l15;
        out[(size_t)t * HD + d] = v + bias;
      }
    }
  }
}

extern "C" void kernel_launch(void* const* d_in, const int* in_sizes, int n_in,
                              void* d_out, int out_size, void* d_ws, size_t ws_size,
                              hipStream_t stream) {
  const float* x  = (const float*)d_in[0];   // [4,2048,1024]
  const float* gw = (const float*)d_in[1];   // [1024,8]
  const float* gb = (const float*)d_in[2];   // [8]
  const float* ew = (const float*)d_in[3];   // [8,1024,1024]
  const float* eb = (const float*)d_in[4];   // [8,1024]
  float* out = (float*)d_out;                // [4,2048,1024] fp32

  char* ws = (char*)d_ws;
  u16*   abf   = (u16*)ws;                                // 16 MB bf16 x
  u16*   wt    = (u16*)(ws + (size_t)16 * 1024 * 1024);   // 16 MB bf16 Wt
  float* wgate = (float*)(ws + (size_t)32 * 1024 * 1024); // 256 KB gate weights

  gate_conv_kernel<<<dim3(TTOK / 4), dim3(256), 0, stream>>>(x, gw, gb, wgate, abf);
  wconv_kernel<<<dim3(16, 16, 8), dim3(256), 0, stream>>>(ew, wt);
  moe_gemm_kernel<<<dim3((TTOK / BM) * (HD / BN)), dim3(512), 0, stream>>>(abf, wt, wgate, eb, out);
}